// Round 1
// 699.053 us; speedup vs baseline: 1.3994x; 1.3994x over previous
//
#include <hip/hip_runtime.h>
#include <hip/hip_bf16.h>
#include <cstdint>

// Problem constants
#define T_SEQ  4096
#define DMODEL 512
#define DINNER 1024
#define MTOT   32768            // B*T = 8*4096 rows

typedef __bf16 bf16_t;
typedef bf16_t bf16x8 __attribute__((ext_vector_type(8)));
typedef bf16_t bf16x4v __attribute__((ext_vector_type(4)));
typedef float  f32x4  __attribute__((ext_vector_type(4)));

__device__ __forceinline__ void async_copy16(const bf16_t* g, bf16_t* l) {
  __builtin_amdgcn_global_load_lds(
      (const __attribute__((address_space(1))) void*)g,
      (__attribute__((address_space(3))) void*)l,
      16, 0, 0);
}

__device__ __forceinline__ float silu_f(float v) {
  return v / (1.f + __expf(-v));
}

// fp32 -> bf16 cast, 4 elements/thread
__global__ __launch_bounds__(256) void cast_kernel(
    const float* __restrict__ s, bf16_t* __restrict__ d, int n4)
{
  const int i = blockIdx.x * 256 + threadIdx.x;
  if (i < n4) {
    const f32x4 v = ((const f32x4*)s)[i];
    bf16x4v o;
    o[0] = (bf16_t)v[0]; o[1] = (bf16_t)v[1];
    o[2] = (bf16_t)v[2]; o[3] = (bf16_t)v[3];
    ((bf16x4v*)d)[i] = o;
  }
}

// Transpose conv weight (DINNER,1,7) [c][k] -> wt[k][c] (7 x 1024 f32)
__global__ __launch_bounds__(256) void wtr_kernel(
    const float* __restrict__ w, float* __restrict__ wt)
{
  const int i = blockIdx.x * 256 + threadIdx.x;   // 7*1024 = 7168
  if (i < 7 * DINNER) {
    const int c = i & (DINNER - 1);
    const int k = i >> 10;
    wt[i] = w[c * 7 + k];
  }
}

// MFMA GEMM (m97 structure): C[m,n] = sum_k A[m,k]*B[n,k]
// A: MxK row-major bf16, B: NxK row-major bf16.
// EPI 0: plain bf16 store
// EPI 1: +bias(f32), silu, bf16 store
// EPI 2: +resid(f32), f32 store
template <int EPI>
__global__ __launch_bounds__(256, 2) void gemm_bt(
    const bf16_t* __restrict__ A, const bf16_t* __restrict__ B,
    bf16_t* __restrict__ Cb, float* __restrict__ Cf,
    const float* __restrict__ bias, const float* __restrict__ resid,
    int N, int K)
{
  constexpr int BM = 128, BN = 128, BK = 64;
  __shared__ __attribute__((aligned(16))) bf16_t sA[BM * BK];
  __shared__ __attribute__((aligned(16))) bf16_t sB[BN * BK];

  const int tid  = threadIdx.x;
  const int m0   = blockIdx.y * BM;
  const int n0   = blockIdx.x * BN;
  const int w    = tid >> 6, lane = tid & 63;
  const int wm   = (w & 1) << 6, wn = (w >> 1) << 6;   // 2x2 waves -> 64x64 each
  const int quad = lane >> 4, lrow = lane & 15;

  f32x4 acc[4][4] = {};

  for (int kt = 0; kt < K; kt += BK) {
    __syncthreads();   // protect LDS while prior tile in use
#pragma unroll
    for (int i = 0; i < 4; ++i) {
      const int f = (i * 256 + tid) << 3;    // flat bf16 index in 128x64 tile
      const int r = f >> 6, c = f & 63;
      async_copy16(&A[(size_t)(m0 + r) * K + kt + c], &sA[f]);
      async_copy16(&B[(size_t)(n0 + r) * K + kt + c], &sB[f]);
    }
    __syncthreads();   // vmcnt(0) drain happens here
#pragma unroll
    for (int ks = 0; ks < 2; ++ks) {
      bf16x8 av[4], bv[4];
#pragma unroll
      for (int i = 0; i < 4; ++i) {
        av[i] = *(const bf16x8*)&sA[(wm + i * 16 + lrow) * BK + ks * 32 + (quad << 3)];
        bv[i] = *(const bf16x8*)&sB[(wn + i * 16 + lrow) * BK + ks * 32 + (quad << 3)];
      }
#pragma unroll
      for (int mi = 0; mi < 4; ++mi)
#pragma unroll
        for (int ni = 0; ni < 4; ++ni)
          acc[mi][ni] = __builtin_amdgcn_mfma_f32_16x16x32_bf16(
              av[mi], bv[ni], acc[mi][ni], 0, 0, 0);
    }
  }

  // C/D layout: col = lane&15, row = quad*4 + reg   [m89/m91 verified]
#pragma unroll
  for (int mi = 0; mi < 4; ++mi)
#pragma unroll
    for (int ni = 0; ni < 4; ++ni)
#pragma unroll
      for (int r = 0; r < 4; ++r) {
        const int row = m0 + wm + mi * 16 + (quad << 2) + r;
        const int col = n0 + wn + ni * 16 + lrow;
        float v = acc[mi][ni][r];
        if constexpr (EPI == 0) {
          Cb[(size_t)row * N + col] = (bf16_t)v;
        } else if constexpr (EPI == 1) {
          v += bias[col];
          Cb[(size_t)row * N + col] = (bf16_t)silu_f(v);
        } else {
          v += resid[(size_t)row * N + col];
          Cf[(size_t)row * N + col] = v;
        }
      }
}

// Depthwise causal conv, one direction, shift_right folded in.
// Register-blocked + vectorized: each thread = 4 consecutive t x 8 channels.
//   fwd (DIR=0): out[t] = b + sum_k w[k]*xp[t-7+k]   (tap valid iff t-7+k >= 0 in-seq)
//   bwd (DIR=1): out[t] = b + sum_k w[k]*xp[t+7-k]   (tap valid iff t+7-k <= T-1 in-seq)
// wt is the transposed weight table [k][c] (f32). Rows clamped to [0,Mc-1];
// clamped rows only occur where the corresponding taps are masked.
template <int DIR>
__global__ __launch_bounds__(256) void conv_kernel(
    const bf16_t* __restrict__ xzc,
    const float* __restrict__ wt, const float* __restrict__ bc,
    bf16_t* __restrict__ vout, int r0, int loc0, int Mc)
{
  const int idx = blockIdx.x * 256 + threadIdx.x;   // over CH*DINNER/32
  const int c8  = idx & 127;                        // 8-channel group
  const int tg  = idx >> 7;                         // 4-row time group
  const int bt0 = tg << 2;                          // chunk-local first row
  const int t0  = (bt0 + r0) & (T_SEQ - 1);         // in-sequence t of first row
  const int lt0 = bt0 + loc0;                       // local row in xzc
  const int cc  = c8 << 3;

  // weights: 7 taps x 8 channels, from transposed table (contiguous f32x4 pairs)
  float wv[7][8];
#pragma unroll
  for (int k = 0; k < 7; ++k) {
    const f32x4 a = *(const f32x4*)&wt[k * DINNER + cc];
    const f32x4 b = *(const f32x4*)&wt[k * DINNER + cc + 4];
#pragma unroll
    for (int u = 0; u < 4; ++u) { wv[k][u] = a[u]; wv[k][u + 4] = b[u]; }
  }

  float acc[4][8];
  {
    const f32x4 a = *(const f32x4*)&bc[cc];
    const f32x4 b = *(const f32x4*)&bc[cc + 4];
#pragma unroll
    for (int i = 0; i < 4; ++i)
#pragma unroll
      for (int u = 0; u < 4; ++u) { acc[i][u] = a[u]; acc[i][u + 4] = b[u]; }
  }

  // fwd: rows t0-7 .. t0+2 ; bwd: rows t0+1 .. t0+10   (10 rows either way)
#pragma unroll
  for (int rr = 0; rr < 10; ++rr) {
    int lt = (DIR == 0) ? (lt0 - 7 + rr) : (lt0 + 1 + rr);
    lt = lt < 0 ? 0 : (lt > Mc - 1 ? Mc - 1 : lt);
    const bf16x8 xv = *(const bf16x8*)&xzc[(size_t)lt * 2048 + cc];
    float xf[8];
#pragma unroll
    for (int u = 0; u < 8; ++u) xf[u] = (float)xv[u];
#pragma unroll
    for (int i = 0; i < 4; ++i) {
      // tap index for output i consuming this row (compile-time after unroll)
      const int k = (DIR == 0) ? (rr - i) : (i + 6 - rr);
      if (k >= 0 && k <= 6) {
        // wave-uniform sequence-edge mask
        const bool ok = (DIR == 0) ? (t0 + i >= 7 - k)
                                   : (t0 + i <= (T_SEQ - 8) + k);
        if (ok) {
#pragma unroll
          for (int u = 0; u < 8; ++u) acc[i][u] += wv[k][u] * xf[u];
        }
      }
    }
  }

#pragma unroll
  for (int i = 0; i < 4; ++i) {
    bf16x8 o;
#pragma unroll
    for (int u = 0; u < 8; ++u) o[u] = (bf16_t)acc[i][u];
    *(bf16x8*)&vout[(size_t)(bt0 + i) * DINNER + cc] = o;
  }
}

// g = (sf*[t>0] + sb*[t<T-1] + xp*diag) * silu(z) * gs  -> in-place over sb
// Vectorized: 8 channels/thread.
__global__ __launch_bounds__(256) void gate_kernel(
    const bf16_t* __restrict__ xzc,
    const bf16_t* __restrict__ sf, bf16_t* __restrict__ sb_g,
    const float* __restrict__ diag, const float* __restrict__ gs,
    int r0, int loc0)
{
  const int idx = blockIdx.x * 256 + threadIdx.x;   // over CH*DINNER/8
  const int e8  = idx & 127;
  const int btl = idx >> 7;
  const int t   = (btl + r0) & (T_SEQ - 1);
  const int lt  = btl + loc0;
  const int ee  = e8 << 3;

  const bf16x8 xp  = *(const bf16x8*)&xzc[(size_t)lt * 2048 + ee];
  const bf16x8 zz  = *(const bf16x8*)&xzc[(size_t)lt * 2048 + DINNER + ee];
  const bf16x8 sfv = *(const bf16x8*)&sf[(size_t)btl * DINNER + ee];
  const bf16x8 sbv = *(const bf16x8*)&sb_g[(size_t)btl * DINNER + ee];
  const f32x4 d0 = *(const f32x4*)&diag[ee];
  const f32x4 d1 = *(const f32x4*)&diag[ee + 4];
  const float g = gs[0];
  const bool addf = (t > 0), addb = (t < T_SEQ - 1);

  bf16x8 o;
#pragma unroll
  for (int u = 0; u < 8; ++u) {
    float y = (float)xp[u] * (u < 4 ? d0[u] : d1[u - 4]);
    if (addf) y += (float)sfv[u];
    if (addb) y += (float)sbv[u];
    o[u] = (bf16_t)(y * silu_f((float)zz[u]) * g);
  }
  *(bf16x8*)&sb_g[(size_t)btl * DINNER + ee] = o;
}

// LayerNorm over D=512, one block (256 threads) per chunk-local row.
// h fp32 in, fp32 out.
__global__ __launch_bounds__(256) void ln_kernel(
    const float* __restrict__ h,
    const float* __restrict__ lng, const float* __restrict__ lnb,
    float* __restrict__ out, int r0)
{
  const int row = blockIdx.x;                        // local row
  const int tid = threadIdx.x;
  const float* hr = h + (size_t)row * DMODEL;
  const float v0 = hr[tid], v1 = hr[tid + 256];
  float s  = v0 + v1;
  float ss = v0 * v0 + v1 * v1;
#pragma unroll
  for (int off = 1; off < 64; off <<= 1) {
    s  += __shfl_xor(s, off);
    ss += __shfl_xor(ss, off);
  }
  __shared__ float ps[8];
  const int w = tid >> 6;
  if ((tid & 63) == 0) { ps[w] = s; ps[w + 4] = ss; }
  __syncthreads();
  s  = ps[0] + ps[1] + ps[2] + ps[3];
  ss = ps[4] + ps[5] + ps[6] + ps[7];
  const float mu  = s * (1.f / DMODEL);
  const float inv = rsqrtf(ss * (1.f / DMODEL) - mu * mu + 1e-5f);
  float* o = out + (size_t)(r0 + row) * DMODEL;
  o[tid]       = (v0 - mu) * inv * lng[tid]       + lnb[tid];
  o[tid + 256] = (v1 - mu) * inv * lng[tid + 256] + lnb[tid + 256];
}

extern "C" void kernel_launch(void* const* d_in, const int* in_sizes, int n_in,
                              void* d_out, int out_size, void* d_ws, size_t ws_size,
                              hipStream_t stream) {
  // Inputs fp32; OUTPUT fp32 (verified passing in R7).
  const float* x    = (const float*)d_in[0];
  const float* in_w = (const float*)d_in[1];
  const float* cfw  = (const float*)d_in[2];
  const float* cfb  = (const float*)d_in[3];
  const float* pfw  = (const float*)d_in[4];
  const float* pfb  = (const float*)d_in[5];
  const float* cbw  = (const float*)d_in[6];
  const float* cbb  = (const float*)d_in[7];
  const float* pbw  = (const float*)d_in[8];
  const float* pbb  = (const float*)d_in[9];
  const float* diag = (const float*)d_in[10];
  const float* gs   = (const float*)d_in[11];
  const float* ow   = (const float*)d_in[12];
  const float* lng  = (const float*)d_in[13];
  const float* lnb  = (const float*)d_in[14];
  float* out = (float*)d_out;

  char* ws = (char*)d_ws;

  // Persistent bf16 copies of GEMM operand tensors + transposed conv weights:
  bf16_t* xw   = (bf16_t*)(ws);                         // 32768x512   (32 MiB)
  bf16_t* inwb = (bf16_t*)(ws + (size_t)33554432);      // 2048x512    (2 MiB)
  bf16_t* pfwb = (bf16_t*)(ws + (size_t)35651584);      // 1024x1024   (2 MiB)
  bf16_t* pbwb = (bf16_t*)(ws + (size_t)37748736);      // 1024x1024   (2 MiB)
  bf16_t* owb  = (bf16_t*)(ws + (size_t)39845888);      // 512x1024    (1 MiB)
  float*  wtf  = (float*)(ws + (size_t)40894464);       // 7x1024 f32  (28 KiB)
  float*  wtb  = (float*)(ws + (size_t)40923136);       // 7x1024 f32  (28 KiB)
  const size_t persist = 40951808;

  // Workspace-adaptive chunking.
  // req(CH) = persist + (CH+256)*4096 + 3*CH*2048 bytes
  int CH = 128;
  {
    const int cands[8] = {16384, 8192, 4096, 2048, 1024, 512, 256, 128};
    for (int i = 0; i < 8; ++i) {
      const size_t req = persist + (size_t)(cands[i] + 256) * 4096 +
                         (size_t)3 * cands[i] * 2048;
      if (ws_size >= req) { CH = cands[i]; break; }
    }
  }

  char* cb = ws + persist;
  const size_t xz_cap = (size_t)(CH + 256) * 4096;      // bytes
  bf16_t* xzc  = (bf16_t*)cb;
  bf16_t* bufA = (bf16_t*)(cb + xz_cap);
  bf16_t* bufB = (bf16_t*)(cb + xz_cap + (size_t)CH * 2048);
  bf16_t* bufC = (bf16_t*)(cb + xz_cap + (size_t)CH * 4096);
  float*  hbuf = (float*)cb;                             // aliases xzc (dead by then)

  dim3 blk(256);

  // 0) one-time fp32 -> bf16 casts of GEMM operands + conv-weight transposes
  cast_kernel<<<dim3(16384), blk, 0, stream>>>(x,    xw,   4194304);
  cast_kernel<<<dim3(1024),  blk, 0, stream>>>(in_w, inwb, 262144);
  cast_kernel<<<dim3(1024),  blk, 0, stream>>>(pfw,  pfwb, 262144);
  cast_kernel<<<dim3(1024),  blk, 0, stream>>>(pbw,  pbwb, 262144);
  cast_kernel<<<dim3(512),   blk, 0, stream>>>(ow,   owb,  131072);
  wtr_kernel<<<dim3(28), blk, 0, stream>>>(cfw, wtf);
  wtr_kernel<<<dim3(28), blk, 0, stream>>>(cbw, wtb);

  for (int r0 = 0; r0 < MTOT; r0 += CH) {
    const int g0 = (r0 >= 128) ? (r0 - 128) : 0;
    int g1 = r0 + CH + 128; if (g1 > MTOT) g1 = MTOT;
    const int Mc   = g1 - g0;        // multiple of 128
    const int loc0 = r0 - g0;        // chunk start's local row in xzc

    // 1) xzc = x[g0:g1] @ in_proj_w^T        (Mc x 2048, K=512)
    gemm_bt<0><<<dim3(2048 / 128, Mc / 128), blk, 0, stream>>>(
        xw + (size_t)g0 * 512, inwb, xzc, nullptr, nullptr, nullptr, 2048, 512);

    // 2) forward shifted causal conv -> v_fwd (bufA)
    conv_kernel<0><<<dim3(CH / 8), blk, 0, stream>>>(
        xzc, wtf, cfb, bufA, r0, loc0, Mc);

    // 3) s_fwd = silu(v_fwd @ Pf^T + bf) -> bufB   (N=1024, K=1024)
    gemm_bt<1><<<dim3(1024 / 128, CH / 128), blk, 0, stream>>>(
        bufA, pfwb, bufB, nullptr, pfb, nullptr, 1024, 1024);

    // 4) backward shifted causal conv -> v_bwd (bufA, v_fwd dead)
    conv_kernel<1><<<dim3(CH / 8), blk, 0, stream>>>(
        xzc, wtb, cbb, bufA, r0, loc0, Mc);

    // 5) s_bwd = silu(v_bwd @ Pb^T + bb) -> bufC
    gemm_bt<1><<<dim3(1024 / 128, CH / 128), blk, 0, stream>>>(
        bufA, pbwb, bufC, nullptr, pbb, nullptr, 1024, 1024);

    // 6) gate: g = (sf*[t>0]+sb*[t<T-1]+xp*diag)*silu(z)*gs -> bufC in-place
    gate_kernel<<<dim3(CH / 2), blk, 0, stream>>>(
        xzc, bufB, bufC, diag, gs, r0, loc0);

    // 7) h = x + g @ out_proj^T (fp32) -> hbuf (aliases xzc; xz dead now)
    gemm_bt<2><<<dim3(512 / 128, CH / 128), blk, 0, stream>>>(
        bufC, owb, nullptr, hbuf, nullptr, x + (size_t)r0 * 512, 512, 1024);

    // 8) LayerNorm -> out rows [r0, r0+CH)   (fp32 store)
    ln_kernel<<<dim3(CH), blk, 0, stream>>>(hbuf, lng, lnb, out, r0);
  }
}

// Round 2
// 680.087 us; speedup vs baseline: 1.4384x; 1.0279x over previous
//
#include <hip/hip_runtime.h>
#include <hip/hip_bf16.h>
#include <cstdint>

// Problem constants
#define T_SEQ  4096
#define DMODEL 512
#define DINNER 1024
#define MTOT   32768            // B*T = 8*4096 rows

typedef __bf16 bf16_t;
typedef bf16_t bf16x8 __attribute__((ext_vector_type(8)));
typedef bf16_t bf16x4v __attribute__((ext_vector_type(4)));
typedef float  f32x4  __attribute__((ext_vector_type(4)));

__device__ __forceinline__ void async_copy16(const bf16_t* g, bf16_t* l) {
  __builtin_amdgcn_global_load_lds(
      (const __attribute__((address_space(1))) void*)g,
      (__attribute__((address_space(3))) void*)l,
      16, 0, 0);
}

__device__ __forceinline__ float silu_f(float v) {
  return v / (1.f + __expf(-v));
}

// fp32 -> bf16 cast, 4 elements/thread
__global__ __launch_bounds__(256) void cast_kernel(
    const float* __restrict__ s, bf16_t* __restrict__ d, int n4)
{
  const int i = blockIdx.x * 256 + threadIdx.x;
  if (i < n4) {
    const f32x4 v = ((const f32x4*)s)[i];
    bf16x4v o;
    o[0] = (bf16_t)v[0]; o[1] = (bf16_t)v[1];
    o[2] = (bf16_t)v[2]; o[3] = (bf16_t)v[3];
    ((bf16x4v*)d)[i] = o;
  }
}

// Transpose conv weight (DINNER,1,7) [c][k] -> wt[k][c] (7 x 1024 f32)
__global__ __launch_bounds__(256) void wtr_kernel(
    const float* __restrict__ w, float* __restrict__ wt)
{
  const int i = blockIdx.x * 256 + threadIdx.x;   // 7*1024 = 7168
  if (i < 7 * DINNER) {
    const int c = i & (DINNER - 1);
    const int k = i >> 10;
    wt[i] = w[c * 7 + k];
  }
}

// MFMA GEMM (m97 structure + T1 XCD swizzle): C[m,n] = sum_k A[m,k]*B[n,k]
// A: MxK row-major bf16, B: NxK row-major bf16.
// EPI 0: plain bf16 store
// EPI 1: +bias(f32), silu, bf16 store
// EPI 2: +resid(f32), f32 store
template <int EPI>
__global__ __launch_bounds__(256, 2) void gemm_bt(
    const bf16_t* __restrict__ A, const bf16_t* __restrict__ B,
    bf16_t* __restrict__ Cb, float* __restrict__ Cf,
    const float* __restrict__ bias, const float* __restrict__ resid,
    int N, int K)
{
  constexpr int BM = 128, BN = 128, BK = 64;
  __shared__ __attribute__((aligned(16))) bf16_t sA[BM * BK];
  __shared__ __attribute__((aligned(16))) bf16_t sB[BN * BK];

  const int tid  = threadIdx.x;

  // T1: bijective XCD-aware block swizzle (m204 form; grids here may have
  // nwg % 8 != 0). HW round-robins dispatch order across the 8 XCDs; remap
  // so each XCD gets a CONTIGUOUS x-fastest tile range -> A row-panel and B
  // stay resident in that XCD's private L2 instead of being re-fetched from
  // HBM once per N-tile (was 16x A over-fetch, FETCH 133 MB vs 10.6 MB ideal).
  int bflat;
  {
    const int nwg = gridDim.x * gridDim.y;
    const int orig = blockIdx.y * gridDim.x + blockIdx.x;
    const int q = nwg >> 3, r = nwg & 7;
    const int xcd = orig & 7, lid = orig >> 3;
    bflat = (xcd < r ? xcd * (q + 1) : r * (q + 1) + (xcd - r) * q) + lid;
  }
  const int m0 = (bflat / gridDim.x) * BM;
  const int n0 = (bflat % gridDim.x) * BN;

  const int w    = tid >> 6, lane = tid & 63;
  const int wm   = (w & 1) << 6, wn = (w >> 1) << 6;   // 2x2 waves -> 64x64 each
  const int quad = lane >> 4, lrow = lane & 15;

  f32x4 acc[4][4] = {};

  for (int kt = 0; kt < K; kt += BK) {
    __syncthreads();   // protect LDS while prior tile in use
#pragma unroll
    for (int i = 0; i < 4; ++i) {
      const int f = (i * 256 + tid) << 3;    // flat bf16 index in 128x64 tile
      const int r = f >> 6, c = f & 63;
      async_copy16(&A[(size_t)(m0 + r) * K + kt + c], &sA[f]);
      async_copy16(&B[(size_t)(n0 + r) * K + kt + c], &sB[f]);
    }
    __syncthreads();   // vmcnt(0) drain happens here
#pragma unroll
    for (int ks = 0; ks < 2; ++ks) {
      bf16x8 av[4], bv[4];
#pragma unroll
      for (int i = 0; i < 4; ++i) {
        av[i] = *(const bf16x8*)&sA[(wm + i * 16 + lrow) * BK + ks * 32 + (quad << 3)];
        bv[i] = *(const bf16x8*)&sB[(wn + i * 16 + lrow) * BK + ks * 32 + (quad << 3)];
      }
#pragma unroll
      for (int mi = 0; mi < 4; ++mi)
#pragma unroll
        for (int ni = 0; ni < 4; ++ni)
          acc[mi][ni] = __builtin_amdgcn_mfma_f32_16x16x32_bf16(
              av[mi], bv[ni], acc[mi][ni], 0, 0, 0);
    }
  }

  // C/D layout: col = lane&15, row = quad*4 + reg   [m89/m91 verified]
#pragma unroll
  for (int mi = 0; mi < 4; ++mi)
#pragma unroll
    for (int ni = 0; ni < 4; ++ni)
#pragma unroll
      for (int r = 0; r < 4; ++r) {
        const int row = m0 + wm + mi * 16 + (quad << 2) + r;
        const int col = n0 + wn + ni * 16 + lrow;
        float v = acc[mi][ni][r];
        if constexpr (EPI == 0) {
          Cb[(size_t)row * N + col] = (bf16_t)v;
        } else if constexpr (EPI == 1) {
          v += bias[col];
          Cb[(size_t)row * N + col] = (bf16_t)silu_f(v);
        } else {
          v += resid[(size_t)row * N + col];
          Cf[(size_t)row * N + col] = v;
        }
      }
}

// Depthwise causal conv, one direction, shift_right folded in.
// Register-blocked + vectorized: each thread = 4 consecutive t x 8 channels.
//   fwd (DIR=0): out[t] = b + sum_k w[k]*xp[t-7+k]   (tap valid iff t-7+k >= 0 in-seq)
//   bwd (DIR=1): out[t] = b + sum_k w[k]*xp[t+7-k]   (tap valid iff t+7-k <= T-1 in-seq)
// wt is the transposed weight table [k][c] (f32). Rows clamped to [0,Mc-1];
// clamped rows only occur where the corresponding taps are masked.
template <int DIR>
__global__ __launch_bounds__(256) void conv_kernel(
    const bf16_t* __restrict__ xzc,
    const float* __restrict__ wt, const float* __restrict__ bc,
    bf16_t* __restrict__ vout, int r0, int loc0, int Mc)
{
  const int idx = blockIdx.x * 256 + threadIdx.x;   // over CH*DINNER/32
  const int c8  = idx & 127;                        // 8-channel group
  const int tg  = idx >> 7;                         // 4-row time group
  const int bt0 = tg << 2;                          // chunk-local first row
  const int t0  = (bt0 + r0) & (T_SEQ - 1);         // in-sequence t of first row
  const int lt0 = bt0 + loc0;                       // local row in xzc
  const int cc  = c8 << 3;

  // weights: 7 taps x 8 channels, from transposed table (contiguous f32x4 pairs)
  float wv[7][8];
#pragma unroll
  for (int k = 0; k < 7; ++k) {
    const f32x4 a = *(const f32x4*)&wt[k * DINNER + cc];
    const f32x4 b = *(const f32x4*)&wt[k * DINNER + cc + 4];
#pragma unroll
    for (int u = 0; u < 4; ++u) { wv[k][u] = a[u]; wv[k][u + 4] = b[u]; }
  }

  float acc[4][8];
  {
    const f32x4 a = *(const f32x4*)&bc[cc];
    const f32x4 b = *(const f32x4*)&bc[cc + 4];
#pragma unroll
    for (int i = 0; i < 4; ++i)
#pragma unroll
      for (int u = 0; u < 4; ++u) { acc[i][u] = a[u]; acc[i][u + 4] = b[u]; }
  }

  // fwd: rows t0-7 .. t0+2 ; bwd: rows t0+1 .. t0+10   (10 rows either way)
#pragma unroll
  for (int rr = 0; rr < 10; ++rr) {
    int lt = (DIR == 0) ? (lt0 - 7 + rr) : (lt0 + 1 + rr);
    lt = lt < 0 ? 0 : (lt > Mc - 1 ? Mc - 1 : lt);
    const bf16x8 xv = *(const bf16x8*)&xzc[(size_t)lt * 2048 + cc];
    float xf[8];
#pragma unroll
    for (int u = 0; u < 8; ++u) xf[u] = (float)xv[u];
#pragma unroll
    for (int i = 0; i < 4; ++i) {
      // tap index for output i consuming this row (compile-time after unroll)
      const int k = (DIR == 0) ? (rr - i) : (i + 6 - rr);
      if (k >= 0 && k <= 6) {
        // wave-uniform sequence-edge mask
        const bool ok = (DIR == 0) ? (t0 + i >= 7 - k)
                                   : (t0 + i <= (T_SEQ - 8) + k);
        if (ok) {
#pragma unroll
          for (int u = 0; u < 8; ++u) acc[i][u] += wv[k][u] * xf[u];
        }
      }
    }
  }

#pragma unroll
  for (int i = 0; i < 4; ++i) {
    bf16x8 o;
#pragma unroll
    for (int u = 0; u < 8; ++u) o[u] = (bf16_t)acc[i][u];
    *(bf16x8*)&vout[(size_t)(bt0 + i) * DINNER + cc] = o;
  }
}

// g = (sf*[t>0] + sb*[t<T-1] + xp*diag) * silu(z) * gs  -> in-place over sb
// Vectorized: 8 channels/thread.
__global__ __launch_bounds__(256) void gate_kernel(
    const bf16_t* __restrict__ xzc,
    const bf16_t* __restrict__ sf, bf16_t* __restrict__ sb_g,
    const float* __restrict__ diag, const float* __restrict__ gs,
    int r0, int loc0)
{
  const int idx = blockIdx.x * 256 + threadIdx.x;   // over CH*DINNER/8
  const int e8  = idx & 127;
  const int btl = idx >> 7;
  const int t   = (btl + r0) & (T_SEQ - 1);
  const int lt  = btl + loc0;
  const int ee  = e8 << 3;

  const bf16x8 xp  = *(const bf16x8*)&xzc[(size_t)lt * 2048 + ee];
  const bf16x8 zz  = *(const bf16x8*)&xzc[(size_t)lt * 2048 + DINNER + ee];
  const bf16x8 sfv = *(const bf16x8*)&sf[(size_t)btl * DINNER + ee];
  const bf16x8 sbv = *(const bf16x8*)&sb_g[(size_t)btl * DINNER + ee];
  const f32x4 d0 = *(const f32x4*)&diag[ee];
  const f32x4 d1 = *(const f32x4*)&diag[ee + 4];
  const float g = gs[0];
  const bool addf = (t > 0), addb = (t < T_SEQ - 1);

  bf16x8 o;
#pragma unroll
  for (int u = 0; u < 8; ++u) {
    float y = (float)xp[u] * (u < 4 ? d0[u] : d1[u - 4]);
    if (addf) y += (float)sfv[u];
    if (addb) y += (float)sbv[u];
    o[u] = (bf16_t)(y * silu_f((float)zz[u]) * g);
  }
  *(bf16x8*)&sb_g[(size_t)btl * DINNER + ee] = o;
}

// LayerNorm over D=512, one block (256 threads) per chunk-local row.
// h fp32 in, fp32 out.
__global__ __launch_bounds__(256) void ln_kernel(
    const float* __restrict__ h,
    const float* __restrict__ lng, const float* __restrict__ lnb,
    float* __restrict__ out, int r0)
{
  const int row = blockIdx.x;                        // local row
  const int tid = threadIdx.x;
  const float* hr = h + (size_t)row * DMODEL;
  const float v0 = hr[tid], v1 = hr[tid + 256];
  float s  = v0 + v1;
  float ss = v0 * v0 + v1 * v1;
#pragma unroll
  for (int off = 1; off < 64; off <<= 1) {
    s  += __shfl_xor(s, off);
    ss += __shfl_xor(ss, off);
  }
  __shared__ float ps[8];
  const int w = tid >> 6;
  if ((tid & 63) == 0) { ps[w] = s; ps[w + 4] = ss; }
  __syncthreads();
  s  = ps[0] + ps[1] + ps[2] + ps[3];
  ss = ps[4] + ps[5] + ps[6] + ps[7];
  const float mu  = s * (1.f / DMODEL);
  const float inv = rsqrtf(ss * (1.f / DMODEL) - mu * mu + 1e-5f);
  float* o = out + (size_t)(r0 + row) * DMODEL;
  o[tid]       = (v0 - mu) * inv * lng[tid]       + lnb[tid];
  o[tid + 256] = (v1 - mu) * inv * lng[tid + 256] + lnb[tid + 256];
}

extern "C" void kernel_launch(void* const* d_in, const int* in_sizes, int n_in,
                              void* d_out, int out_size, void* d_ws, size_t ws_size,
                              hipStream_t stream) {
  // Inputs fp32; OUTPUT fp32 (verified passing in R7).
  const float* x    = (const float*)d_in[0];
  const float* in_w = (const float*)d_in[1];
  const float* cfw  = (const float*)d_in[2];
  const float* cfb  = (const float*)d_in[3];
  const float* pfw  = (const float*)d_in[4];
  const float* pfb  = (const float*)d_in[5];
  const float* cbw  = (const float*)d_in[6];
  const float* cbb  = (const float*)d_in[7];
  const float* pbw  = (const float*)d_in[8];
  const float* pbb  = (const float*)d_in[9];
  const float* diag = (const float*)d_in[10];
  const float* gs   = (const float*)d_in[11];
  const float* ow   = (const float*)d_in[12];
  const float* lng  = (const float*)d_in[13];
  const float* lnb  = (const float*)d_in[14];
  float* out = (float*)d_out;

  char* ws = (char*)d_ws;

  // Persistent bf16 copies of GEMM operand tensors + transposed conv weights:
  bf16_t* xw   = (bf16_t*)(ws);                         // 32768x512   (32 MiB)
  bf16_t* inwb = (bf16_t*)(ws + (size_t)33554432);      // 2048x512    (2 MiB)
  bf16_t* pfwb = (bf16_t*)(ws + (size_t)35651584);      // 1024x1024   (2 MiB)
  bf16_t* pbwb = (bf16_t*)(ws + (size_t)37748736);      // 1024x1024   (2 MiB)
  bf16_t* owb  = (bf16_t*)(ws + (size_t)39845888);      // 512x1024    (1 MiB)
  float*  wtf  = (float*)(ws + (size_t)40894464);       // 7x1024 f32  (28 KiB)
  float*  wtb  = (float*)(ws + (size_t)40923136);       // 7x1024 f32  (28 KiB)
  const size_t persist = 40951808;

  // Workspace-adaptive chunking.
  // req(CH) = persist + (CH+256)*4096 + 3*CH*2048 bytes
  int CH = 128;
  {
    const int cands[8] = {16384, 8192, 4096, 2048, 1024, 512, 256, 128};
    for (int i = 0; i < 8; ++i) {
      const size_t req = persist + (size_t)(cands[i] + 256) * 4096 +
                         (size_t)3 * cands[i] * 2048;
      if (ws_size >= req) { CH = cands[i]; break; }
    }
  }

  char* cb = ws + persist;
  const size_t xz_cap = (size_t)(CH + 256) * 4096;      // bytes
  bf16_t* xzc  = (bf16_t*)cb;
  bf16_t* bufA = (bf16_t*)(cb + xz_cap);
  bf16_t* bufB = (bf16_t*)(cb + xz_cap + (size_t)CH * 2048);
  bf16_t* bufC = (bf16_t*)(cb + xz_cap + (size_t)CH * 4096);
  float*  hbuf = (float*)cb;                             // aliases xzc (dead by then)

  dim3 blk(256);

  // 0) one-time fp32 -> bf16 casts of GEMM operands + conv-weight transposes
  cast_kernel<<<dim3(16384), blk, 0, stream>>>(x,    xw,   4194304);
  cast_kernel<<<dim3(1024),  blk, 0, stream>>>(in_w, inwb, 262144);
  cast_kernel<<<dim3(1024),  blk, 0, stream>>>(pfw,  pfwb, 262144);
  cast_kernel<<<dim3(1024),  blk, 0, stream>>>(pbw,  pbwb, 262144);
  cast_kernel<<<dim3(512),   blk, 0, stream>>>(ow,   owb,  131072);
  wtr_kernel<<<dim3(28), blk, 0, stream>>>(cfw, wtf);
  wtr_kernel<<<dim3(28), blk, 0, stream>>>(cbw, wtb);

  for (int r0 = 0; r0 < MTOT; r0 += CH) {
    const int g0 = (r0 >= 128) ? (r0 - 128) : 0;
    int g1 = r0 + CH + 128; if (g1 > MTOT) g1 = MTOT;
    const int Mc   = g1 - g0;        // multiple of 128
    const int loc0 = r0 - g0;        // chunk start's local row in xzc

    // 1) xzc = x[g0:g1] @ in_proj_w^T        (Mc x 2048, K=512)
    gemm_bt<0><<<dim3(2048 / 128, Mc / 128), blk, 0, stream>>>(
        xw + (size_t)g0 * 512, inwb, xzc, nullptr, nullptr, nullptr, 2048, 512);

    // 2) forward shifted causal conv -> v_fwd (bufA)
    conv_kernel<0><<<dim3(CH / 8), blk, 0, stream>>>(
        xzc, wtf, cfb, bufA, r0, loc0, Mc);

    // 3) s_fwd = silu(v_fwd @ Pf^T + bf) -> bufB   (N=1024, K=1024)
    gemm_bt<1><<<dim3(1024 / 128, CH / 128), blk, 0, stream>>>(
        bufA, pfwb, bufB, nullptr, pfb, nullptr, 1024, 1024);

    // 4) backward shifted causal conv -> v_bwd (bufA, v_fwd dead)
    conv_kernel<1><<<dim3(CH / 8), blk, 0, stream>>>(
        xzc, wtb, cbb, bufA, r0, loc0, Mc);

    // 5) s_bwd = silu(v_bwd @ Pb^T + bb) -> bufC
    gemm_bt<1><<<dim3(1024 / 128, CH / 128), blk, 0, stream>>>(
        bufA, pbwb, bufC, nullptr, pbb, nullptr, 1024, 1024);

    // 6) gate: g = (sf*[t>0]+sb*[t<T-1]+xp*diag)*silu(z)*gs -> bufC in-place
    gate_kernel<<<dim3(CH / 2), blk, 0, stream>>>(
        xzc, bufB, bufC, diag, gs, r0, loc0);

    // 7) h = x + g @ out_proj^T (fp32) -> hbuf (aliases xzc; xz dead now)
    gemm_bt<2><<<dim3(512 / 128, CH / 128), blk, 0, stream>>>(
        bufC, owb, nullptr, hbuf, nullptr, x + (size_t)r0 * 512, 512, 1024);

    // 8) LayerNorm -> out rows [r0, r0+CH)   (fp32 store)
    ln_kernel<<<dim3(CH), blk, 0, stream>>>(hbuf, lng, lnb, out, r0);
  }
}

// Round 3
// 647.341 us; speedup vs baseline: 1.5112x; 1.0506x over previous
//
#include <hip/hip_runtime.h>
#include <hip/hip_bf16.h>
#include <cstdint>

// Problem constants
#define T_SEQ  4096
#define DMODEL 512
#define DINNER 1024
#define MTOT   32768            // B*T = 8*4096 rows

typedef __bf16 bf16_t;
typedef bf16_t bf16x8 __attribute__((ext_vector_type(8)));
typedef bf16_t bf16x4v __attribute__((ext_vector_type(4)));
typedef float  f32x4  __attribute__((ext_vector_type(4)));

__device__ __forceinline__ void async_copy16(const bf16_t* g, bf16_t* l) {
  __builtin_amdgcn_global_load_lds(
      (const __attribute__((address_space(1))) void*)g,
      (__attribute__((address_space(3))) void*)l,
      16, 0, 0);
}

__device__ __forceinline__ float silu_f(float v) {
  return v / (1.f + __expf(-v));
}

// T1: bijective XCD-aware block swizzle (m204 form).
__device__ __forceinline__ int xcd_swizzle_flat() {
  const int nwg = gridDim.x * gridDim.y;
  const int orig = blockIdx.y * gridDim.x + blockIdx.x;
  const int q = nwg >> 3, r = nwg & 7;
  const int xcd = orig & 7, lid = orig >> 3;
  return (xcd < r ? xcd * (q + 1) : r * (q + 1) + (xcd - r) * q) + lid;
}

// fp32 -> bf16 cast, 4 elements/thread
__global__ __launch_bounds__(256) void cast_kernel(
    const float* __restrict__ s, bf16_t* __restrict__ d, int n4)
{
  const int i = blockIdx.x * 256 + threadIdx.x;
  if (i < n4) {
    const f32x4 v = ((const f32x4*)s)[i];
    bf16x4v o;
    o[0] = (bf16_t)v[0]; o[1] = (bf16_t)v[1];
    o[2] = (bf16_t)v[2]; o[3] = (bf16_t)v[3];
    ((bf16x4v*)d)[i] = o;
  }
}

// Transpose conv weight (DINNER,1,7) [c][k] -> wt[k][c] (7 x 1024 f32)
__global__ __launch_bounds__(256) void wtr_kernel(
    const float* __restrict__ w, float* __restrict__ wt)
{
  const int i = blockIdx.x * 256 + threadIdx.x;   // 7*1024 = 7168
  if (i < 7 * DINNER) {
    const int c = i & (DINNER - 1);
    const int k = i >> 10;
    wt[i] = w[c * 7 + k];
  }
}

// MFMA GEMM (m97 structure + T1 XCD swizzle): C[m,n] = sum_k A[m,k]*B[n,k]
// A: MxK row-major bf16, B: NxK row-major bf16.
// EPI 0: plain bf16 store
// EPI 2: +resid(f32), f32 store
template <int EPI>
__global__ __launch_bounds__(256, 3) void gemm_bt(
    const bf16_t* __restrict__ A, const bf16_t* __restrict__ B,
    bf16_t* __restrict__ Cb, float* __restrict__ Cf,
    const float* __restrict__ resid,
    int N, int K)
{
  constexpr int BM = 128, BN = 128, BK = 64;
  __shared__ __attribute__((aligned(16))) bf16_t sA[BM * BK];
  __shared__ __attribute__((aligned(16))) bf16_t sB[BN * BK];

  const int tid  = threadIdx.x;
  const int bflat = xcd_swizzle_flat();
  const int m0 = (bflat / gridDim.x) * BM;
  const int n0 = (bflat % gridDim.x) * BN;

  const int w    = tid >> 6, lane = tid & 63;
  const int wm   = (w & 1) << 6, wn = (w >> 1) << 6;   // 2x2 waves -> 64x64 each
  const int quad = lane >> 4, lrow = lane & 15;

  f32x4 acc[4][4] = {};

  for (int kt = 0; kt < K; kt += BK) {
    __syncthreads();   // protect LDS while prior tile in use
#pragma unroll
    for (int i = 0; i < 4; ++i) {
      const int f = (i * 256 + tid) << 3;    // flat bf16 index in 128x64 tile
      const int r = f >> 6, c = f & 63;
      async_copy16(&A[(size_t)(m0 + r) * K + kt + c], &sA[f]);
      async_copy16(&B[(size_t)(n0 + r) * K + kt + c], &sB[f]);
    }
    __syncthreads();   // vmcnt(0) drain happens here
#pragma unroll
    for (int ks = 0; ks < 2; ++ks) {
      bf16x8 av[4], bv[4];
#pragma unroll
      for (int i = 0; i < 4; ++i) {
        av[i] = *(const bf16x8*)&sA[(wm + i * 16 + lrow) * BK + ks * 32 + (quad << 3)];
        bv[i] = *(const bf16x8*)&sB[(wn + i * 16 + lrow) * BK + ks * 32 + (quad << 3)];
      }
#pragma unroll
      for (int mi = 0; mi < 4; ++mi)
#pragma unroll
        for (int ni = 0; ni < 4; ++ni)
          acc[mi][ni] = __builtin_amdgcn_mfma_f32_16x16x32_bf16(
              av[mi], bv[ni], acc[mi][ni], 0, 0, 0);
    }
  }

  // C/D layout: col = lane&15, row = quad*4 + reg   [m89/m91 verified]
#pragma unroll
  for (int mi = 0; mi < 4; ++mi)
#pragma unroll
    for (int ni = 0; ni < 4; ++ni)
#pragma unroll
      for (int r = 0; r < 4; ++r) {
        const int row = m0 + wm + mi * 16 + (quad << 2) + r;
        const int col = n0 + wn + ni * 16 + lrow;
        float v = acc[mi][ni][r];
        if constexpr (EPI == 0) {
          Cb[(size_t)row * N + col] = (bf16_t)v;
        } else {
          v += resid[(size_t)row * N + col];
          Cf[(size_t)row * N + col] = v;
        }
      }
}

// Fused dual GEMM + gate (steps 3+5+6):
//   sf = silu(A1 @ B1^T + b1)   (in registers)
//   sb = silu(A2 @ B2^T + b2)   (in registers)
//   G  = (sf*[t>0] + sb*[t<T-1] + xp*diag) * silu(z) * gs
// A1 = v_fwd, A2 = v_bwd (M x K bf16), B1 = Pf, B2 = Pb (N x K bf16).
// Doubles MFMA work per barrier pair (attacks the vmcnt(0)-drain stall) and
// keeps sf/sb out of HBM entirely.
__global__ __launch_bounds__(256, 2) void gemm_dual(
    const bf16_t* __restrict__ A1, const bf16_t* __restrict__ A2,
    const bf16_t* __restrict__ B1, const bf16_t* __restrict__ B2,
    const float* __restrict__ b1, const float* __restrict__ b2,
    const bf16_t* __restrict__ xzc, const float* __restrict__ diag,
    const float* __restrict__ gs, bf16_t* __restrict__ G,
    int r0, int loc0, int N, int K)
{
  constexpr int BM = 128, BN = 128, BK = 64;
  __shared__ __attribute__((aligned(16))) bf16_t sA1[BM * BK];
  __shared__ __attribute__((aligned(16))) bf16_t sA2[BM * BK];
  __shared__ __attribute__((aligned(16))) bf16_t sB1[BN * BK];
  __shared__ __attribute__((aligned(16))) bf16_t sB2[BN * BK];

  const int tid  = threadIdx.x;
  const int bflat = xcd_swizzle_flat();
  const int m0 = (bflat / gridDim.x) * BM;
  const int n0 = (bflat % gridDim.x) * BN;

  const int w    = tid >> 6, lane = tid & 63;
  const int wm   = (w & 1) << 6, wn = (w >> 1) << 6;
  const int quad = lane >> 4, lrow = lane & 15;

  f32x4 accf[4][4] = {};
  f32x4 accb[4][4] = {};

  for (int kt = 0; kt < K; kt += BK) {
    __syncthreads();
#pragma unroll
    for (int i = 0; i < 4; ++i) {
      const int f = (i * 256 + tid) << 3;
      const int r = f >> 6, c = f & 63;
      const size_t ga = (size_t)(m0 + r) * K + kt + c;
      const size_t gb = (size_t)(n0 + r) * K + kt + c;
      async_copy16(&A1[ga], &sA1[f]);
      async_copy16(&A2[ga], &sA2[f]);
      async_copy16(&B1[gb], &sB1[f]);
      async_copy16(&B2[gb], &sB2[f]);
    }
    __syncthreads();
#pragma unroll
    for (int ks = 0; ks < 2; ++ks) {
      const int ko = ks * 32 + (quad << 3);
      bf16x8 av[4], bv[4];
#pragma unroll
      for (int i = 0; i < 4; ++i) {
        av[i] = *(const bf16x8*)&sA1[(wm + i * 16 + lrow) * BK + ko];
        bv[i] = *(const bf16x8*)&sB1[(wn + i * 16 + lrow) * BK + ko];
      }
#pragma unroll
      for (int mi = 0; mi < 4; ++mi)
#pragma unroll
        for (int ni = 0; ni < 4; ++ni)
          accf[mi][ni] = __builtin_amdgcn_mfma_f32_16x16x32_bf16(
              av[mi], bv[ni], accf[mi][ni], 0, 0, 0);
#pragma unroll
      for (int i = 0; i < 4; ++i) {
        av[i] = *(const bf16x8*)&sA2[(wm + i * 16 + lrow) * BK + ko];
        bv[i] = *(const bf16x8*)&sB2[(wn + i * 16 + lrow) * BK + ko];
      }
#pragma unroll
      for (int mi = 0; mi < 4; ++mi)
#pragma unroll
        for (int ni = 0; ni < 4; ++ni)
          accb[mi][ni] = __builtin_amdgcn_mfma_f32_16x16x32_bf16(
              av[mi], bv[ni], accb[mi][ni], 0, 0, 0);
    }
  }

  // Epilogue: per-element gate, all in registers.
  const float gsv = gs[0];
  int   colv[4];
  float b1v[4], b2v[4], dgv[4];
#pragma unroll
  for (int ni = 0; ni < 4; ++ni) {
    const int col = n0 + wn + ni * 16 + lrow;
    colv[ni] = col;
    b1v[ni] = b1[col];
    b2v[ni] = b2[col];
    dgv[ni] = diag[col];
  }
#pragma unroll
  for (int mi = 0; mi < 4; ++mi)
#pragma unroll
    for (int r = 0; r < 4; ++r) {
      const int row = m0 + wm + mi * 16 + (quad << 2) + r;
      const int t = (row + r0) & (T_SEQ - 1);
      const bool tf = (t > 0), tb = (t < T_SEQ - 1);
      const bf16_t* xrow = &xzc[(size_t)(loc0 + row) * 2048];
#pragma unroll
      for (int ni = 0; ni < 4; ++ni) {
        const float sf = silu_f(accf[mi][ni][r] + b1v[ni]);
        const float sb = silu_f(accb[mi][ni][r] + b2v[ni]);
        const float xp = (float)xrow[colv[ni]];
        const float z  = (float)xrow[colv[ni] + DINNER];
        float y = xp * dgv[ni];
        if (tf) y += sf;
        if (tb) y += sb;
        G[(size_t)row * N + colv[ni]] = (bf16_t)(y * silu_f(z) * gsv);
      }
    }
}

// Depthwise causal conv, one direction, shift_right folded in.
// Register-blocked + vectorized: each thread = 4 consecutive t x 8 channels.
template <int DIR>
__global__ __launch_bounds__(256) void conv_kernel(
    const bf16_t* __restrict__ xzc,
    const float* __restrict__ wt, const float* __restrict__ bc,
    bf16_t* __restrict__ vout, int r0, int loc0, int Mc)
{
  const int idx = blockIdx.x * 256 + threadIdx.x;   // over CH*DINNER/32
  const int c8  = idx & 127;                        // 8-channel group
  const int tg  = idx >> 7;                         // 4-row time group
  const int bt0 = tg << 2;                          // chunk-local first row
  const int t0  = (bt0 + r0) & (T_SEQ - 1);         // in-sequence t of first row
  const int lt0 = bt0 + loc0;                       // local row in xzc
  const int cc  = c8 << 3;

  float wv[7][8];
#pragma unroll
  for (int k = 0; k < 7; ++k) {
    const f32x4 a = *(const f32x4*)&wt[k * DINNER + cc];
    const f32x4 b = *(const f32x4*)&wt[k * DINNER + cc + 4];
#pragma unroll
    for (int u = 0; u < 4; ++u) { wv[k][u] = a[u]; wv[k][u + 4] = b[u]; }
  }

  float acc[4][8];
  {
    const f32x4 a = *(const f32x4*)&bc[cc];
    const f32x4 b = *(const f32x4*)&bc[cc + 4];
#pragma unroll
    for (int i = 0; i < 4; ++i)
#pragma unroll
      for (int u = 0; u < 4; ++u) { acc[i][u] = a[u]; acc[i][u + 4] = b[u]; }
  }

#pragma unroll
  for (int rr = 0; rr < 10; ++rr) {
    int lt = (DIR == 0) ? (lt0 - 7 + rr) : (lt0 + 1 + rr);
    lt = lt < 0 ? 0 : (lt > Mc - 1 ? Mc - 1 : lt);
    const bf16x8 xv = *(const bf16x8*)&xzc[(size_t)lt * 2048 + cc];
    float xf[8];
#pragma unroll
    for (int u = 0; u < 8; ++u) xf[u] = (float)xv[u];
#pragma unroll
    for (int i = 0; i < 4; ++i) {
      const int k = (DIR == 0) ? (rr - i) : (i + 6 - rr);
      if (k >= 0 && k <= 6) {
        const bool ok = (DIR == 0) ? (t0 + i >= 7 - k)
                                   : (t0 + i <= (T_SEQ - 8) + k);
        if (ok) {
#pragma unroll
          for (int u = 0; u < 8; ++u) acc[i][u] += wv[k][u] * xf[u];
        }
      }
    }
  }

#pragma unroll
  for (int i = 0; i < 4; ++i) {
    bf16x8 o;
#pragma unroll
    for (int u = 0; u < 8; ++u) o[u] = (bf16_t)acc[i][u];
    *(bf16x8*)&vout[(size_t)(bt0 + i) * DINNER + cc] = o;
  }
}

// LayerNorm over D=512, one block (256 threads) per chunk-local row.
__global__ __launch_bounds__(256) void ln_kernel(
    const float* __restrict__ h,
    const float* __restrict__ lng, const float* __restrict__ lnb,
    float* __restrict__ out, int r0)
{
  const int row = blockIdx.x;                        // local row
  const int tid = threadIdx.x;
  const float* hr = h + (size_t)row * DMODEL;
  const float v0 = hr[tid], v1 = hr[tid + 256];
  float s  = v0 + v1;
  float ss = v0 * v0 + v1 * v1;
#pragma unroll
  for (int off = 1; off < 64; off <<= 1) {
    s  += __shfl_xor(s, off);
    ss += __shfl_xor(ss, off);
  }
  __shared__ float ps[8];
  const int w = tid >> 6;
  if ((tid & 63) == 0) { ps[w] = s; ps[w + 4] = ss; }
  __syncthreads();
  s  = ps[0] + ps[1] + ps[2] + ps[3];
  ss = ps[4] + ps[5] + ps[6] + ps[7];
  const float mu  = s * (1.f / DMODEL);
  const float inv = rsqrtf(ss * (1.f / DMODEL) - mu * mu + 1e-5f);
  float* o = out + (size_t)(r0 + row) * DMODEL;
  o[tid]       = (v0 - mu) * inv * lng[tid]       + lnb[tid];
  o[tid + 256] = (v1 - mu) * inv * lng[tid + 256] + lnb[tid + 256];
}

extern "C" void kernel_launch(void* const* d_in, const int* in_sizes, int n_in,
                              void* d_out, int out_size, void* d_ws, size_t ws_size,
                              hipStream_t stream) {
  const float* x    = (const float*)d_in[0];
  const float* in_w = (const float*)d_in[1];
  const float* cfw  = (const float*)d_in[2];
  const float* cfb  = (const float*)d_in[3];
  const float* pfw  = (const float*)d_in[4];
  const float* pfb  = (const float*)d_in[5];
  const float* cbw  = (const float*)d_in[6];
  const float* cbb  = (const float*)d_in[7];
  const float* pbw  = (const float*)d_in[8];
  const float* pbb  = (const float*)d_in[9];
  const float* diag = (const float*)d_in[10];
  const float* gs   = (const float*)d_in[11];
  const float* ow   = (const float*)d_in[12];
  const float* lng  = (const float*)d_in[13];
  const float* lnb  = (const float*)d_in[14];
  float* out = (float*)d_out;

  char* ws = (char*)d_ws;

  // Persistent bf16 copies of GEMM operand tensors + transposed conv weights:
  bf16_t* xw   = (bf16_t*)(ws);                         // 32768x512   (32 MiB)
  bf16_t* inwb = (bf16_t*)(ws + (size_t)33554432);      // 2048x512    (2 MiB)
  bf16_t* pfwb = (bf16_t*)(ws + (size_t)35651584);      // 1024x1024   (2 MiB)
  bf16_t* pbwb = (bf16_t*)(ws + (size_t)37748736);      // 1024x1024   (2 MiB)
  bf16_t* owb  = (bf16_t*)(ws + (size_t)39845888);      // 512x1024    (1 MiB)
  float*  wtf  = (float*)(ws + (size_t)40894464);       // 7x1024 f32  (28 KiB)
  float*  wtb  = (float*)(ws + (size_t)40923136);       // 7x1024 f32  (28 KiB)
  const size_t persist = 40951808;

  // Workspace-adaptive chunking.
  // req(CH) = persist + (CH+256)*4096 + 3*CH*2048 bytes
  int CH = 128;
  {
    const int cands[8] = {16384, 8192, 4096, 2048, 1024, 512, 256, 128};
    for (int i = 0; i < 8; ++i) {
      const size_t req = persist + (size_t)(cands[i] + 256) * 4096 +
                         (size_t)3 * cands[i] * 2048;
      if (ws_size >= req) { CH = cands[i]; break; }
    }
  }

  char* cb = ws + persist;
  const size_t xz_cap = (size_t)(CH + 256) * 4096;      // bytes
  bf16_t* xzc  = (bf16_t*)cb;
  bf16_t* bufA = (bf16_t*)(cb + xz_cap);                 // v_fwd
  bf16_t* bufB = (bf16_t*)(cb + xz_cap + (size_t)CH * 2048);  // v_bwd
  bf16_t* bufC = (bf16_t*)(cb + xz_cap + (size_t)CH * 4096);  // g
  float*  hbuf = (float*)cb;                             // aliases xzc (dead by then)

  dim3 blk(256);

  // 0) one-time fp32 -> bf16 casts of GEMM operands + conv-weight transposes
  cast_kernel<<<dim3(16384), blk, 0, stream>>>(x,    xw,   4194304);
  cast_kernel<<<dim3(1024),  blk, 0, stream>>>(in_w, inwb, 262144);
  cast_kernel<<<dim3(1024),  blk, 0, stream>>>(pfw,  pfwb, 262144);
  cast_kernel<<<dim3(1024),  blk, 0, stream>>>(pbw,  pbwb, 262144);
  cast_kernel<<<dim3(512),   blk, 0, stream>>>(ow,   owb,  131072);
  wtr_kernel<<<dim3(28), blk, 0, stream>>>(cfw, wtf);
  wtr_kernel<<<dim3(28), blk, 0, stream>>>(cbw, wtb);

  for (int r0 = 0; r0 < MTOT; r0 += CH) {
    const int g0 = (r0 >= 128) ? (r0 - 128) : 0;
    int g1 = r0 + CH + 128; if (g1 > MTOT) g1 = MTOT;
    const int Mc   = g1 - g0;        // multiple of 128
    const int loc0 = r0 - g0;        // chunk start's local row in xzc

    // 1) xzc = x[g0:g1] @ in_proj_w^T        (Mc x 2048, K=512)
    gemm_bt<0><<<dim3(2048 / 128, Mc / 128), blk, 0, stream>>>(
        xw + (size_t)g0 * 512, inwb, xzc, nullptr, nullptr, 2048, 512);

    // 2) forward shifted causal conv -> v_fwd (bufA)
    conv_kernel<0><<<dim3(CH / 8), blk, 0, stream>>>(
        xzc, wtf, cfb, bufA, r0, loc0, Mc);

    // 3) backward shifted causal conv -> v_bwd (bufB)
    conv_kernel<1><<<dim3(CH / 8), blk, 0, stream>>>(
        xzc, wtb, cbb, bufB, r0, loc0, Mc);

    // 4) fused: sf/sb GEMMs + gate -> g (bufC)
    gemm_dual<<<dim3(1024 / 128, CH / 128), blk, 0, stream>>>(
        bufA, bufB, pfwb, pbwb, pfb, pbb, xzc, diag, gs, bufC,
        r0, loc0, 1024, 1024);

    // 5) h = x + g @ out_proj^T (fp32) -> hbuf (aliases xzc; xz dead now)
    gemm_bt<2><<<dim3(512 / 128, CH / 128), blk, 0, stream>>>(
        bufC, owb, nullptr, hbuf, x + (size_t)r0 * 512, 512, 1024);

    // 6) LayerNorm -> out rows [r0, r0+CH)   (fp32 store)
    ln_kernel<<<dim3(CH), blk, 0, stream>>>(hbuf, lng, lnb, out, r0);
  }
}